// Round 1
// baseline (7263.795 us; speedup 1.0000x reference)
//
#include <hip/hip_runtime.h>

static constexpr int KIN  = 25;
static constexpr int KOUT = 5;

// ---------------------------------------------------------------------------
// Kernel 1: per-node transforms xl = x@Wl, xr = x@Wr, plus self-loop edge
// contribution used as the INITIALIZER of denom/acc (no memset needed).
// ---------------------------------------------------------------------------
__global__ __launch_bounds__(256) void k_node(
    const float* __restrict__ x,
    const float* __restrict__ Wl, const float* __restrict__ Wr,
    const float* __restrict__ att,
    float* __restrict__ xl, float* __restrict__ xr,
    float* __restrict__ denom, float* __restrict__ acc, int n)
{
    __shared__ float sWl[KIN * KOUT];
    __shared__ float sWr[KIN * KOUT];
    __shared__ float sAtt[KOUT];
    __shared__ float sx[256 * KIN];

    const int tid = threadIdx.x;
    if (tid < KIN * KOUT) { sWl[tid] = Wl[tid]; sWr[tid] = Wr[tid]; }
    if (tid < KOUT) sAtt[tid] = att[tid];

    const int base = blockIdx.x * 256;
    const int cnt  = min(256, n - base);          // nodes in this block
    const size_t xbase = (size_t)base * KIN;
    for (int i = tid; i < cnt * KIN; i += 256) sx[i] = x[xbase + i];
    __syncthreads();

    if (tid >= cnt) return;
    const int node = base + tid;

    float xls[KOUT] = {0.f, 0.f, 0.f, 0.f, 0.f};
    float xrs[KOUT] = {0.f, 0.f, 0.f, 0.f, 0.f};
    const float* xp = &sx[tid * KIN];             // stride 25 -> conflict-free
#pragma unroll
    for (int i = 0; i < KIN; ++i) {
        const float xv = xp[i];
#pragma unroll
        for (int o = 0; o < KOUT; ++o) {
            xls[o] += xv * sWl[i * KOUT + o];
            xrs[o] += xv * sWr[i * KOUT + o];
        }
    }

    // self-loop attention logit: a . lrelu(xl[i] + xr[i], 0.2)
    float e = 0.f;
#pragma unroll
    for (int o = 0; o < KOUT; ++o) {
        float s = xls[o] + xrs[o];
        s = (s >= 0.f) ? s : 0.2f * s;
        e += s * sAtt[o];
    }
    const float w = __expf(e);

    const size_t n5 = (size_t)node * KOUT;
    denom[node] = w;
#pragma unroll
    for (int o = 0; o < KOUT; ++o) {
        xl[n5 + o]  = xls[o];
        xr[n5 + o]  = xrs[o];
        acc[n5 + o] = w * xls[o];
    }
}

// ---------------------------------------------------------------------------
// Kernel 2: per-edge attention + atomic accumulation into denom / acc.
// No max-subtraction: |e| is small enough for fp32 exp (see analysis).
// ---------------------------------------------------------------------------
__global__ __launch_bounds__(256) void k_edge(
    const int* __restrict__ ei, int E,
    const float* __restrict__ xl, const float* __restrict__ xr,
    const float* __restrict__ att,
    float* __restrict__ denom, float* __restrict__ acc)
{
    const int e = blockIdx.x * 256 + threadIdx.x;
    if (e >= E) return;

    const int s = ei[e];         // source j
    const int d = ei[E + e];     // target i

    const float a0 = att[0], a1 = att[1], a2 = att[2], a3 = att[3], a4 = att[4];

    const size_t s5 = (size_t)s * KOUT;
    const size_t d5 = (size_t)d * KOUT;
    const float xs0 = xl[s5 + 0], xs1 = xl[s5 + 1], xs2 = xl[s5 + 2],
                xs3 = xl[s5 + 3], xs4 = xl[s5 + 4];
    const float xd0 = xr[d5 + 0], xd1 = xr[d5 + 1], xd2 = xr[d5 + 2],
                xd3 = xr[d5 + 3], xd4 = xr[d5 + 4];

    float t, logit = 0.f;
    t = xs0 + xd0; t = (t >= 0.f) ? t : 0.2f * t; logit += t * a0;
    t = xs1 + xd1; t = (t >= 0.f) ? t : 0.2f * t; logit += t * a1;
    t = xs2 + xd2; t = (t >= 0.f) ? t : 0.2f * t; logit += t * a2;
    t = xs3 + xd3; t = (t >= 0.f) ? t : 0.2f * t; logit += t * a3;
    t = xs4 + xd4; t = (t >= 0.f) ? t : 0.2f * t; logit += t * a4;

    const float w = __expf(logit);

    atomicAdd(&denom[d], w);
    atomicAdd(&acc[d5 + 0], w * xs0);
    atomicAdd(&acc[d5 + 1], w * xs1);
    atomicAdd(&acc[d5 + 2], w * xs2);
    atomicAdd(&acc[d5 + 3], w * xs3);
    atomicAdd(&acc[d5 + 4], w * xs4);
}

// ---------------------------------------------------------------------------
// Kernel 3: finalize one relation in place: acc/denom + bias, LeakyReLU(0.1)
// ---------------------------------------------------------------------------
__global__ __launch_bounds__(256) void k_fin(
    float* __restrict__ acc, const float* __restrict__ denom,
    const float* __restrict__ b, int n)
{
    const int node = blockIdx.x * 256 + threadIdx.x;
    if (node >= n) return;
    const float inv = 1.0f / denom[node];
    const float b0 = b[0], b1 = b[1], b2 = b[2], b3 = b[3], b4 = b[4];
    const size_t n5 = (size_t)node * KOUT;
    float v;
    v = acc[n5 + 0] * inv + b0; acc[n5 + 0] = (v >= 0.f) ? v : 0.1f * v;
    v = acc[n5 + 1] * inv + b1; acc[n5 + 1] = (v >= 0.f) ? v : 0.1f * v;
    v = acc[n5 + 2] * inv + b2; acc[n5 + 2] = (v >= 0.f) ? v : 0.1f * v;
    v = acc[n5 + 3] * inv + b3; acc[n5 + 3] = (v >= 0.f) ? v : 0.1f * v;
    v = acc[n5 + 4] * inv + b4; acc[n5 + 4] = (v >= 0.f) ? v : 0.1f * v;
}

// ---------------------------------------------------------------------------
// Kernel 4: fused projection + classifier MLP.
// ---------------------------------------------------------------------------
__global__ __launch_bounds__(256) void k_mlp(
    const float* __restrict__ xp, const float* __restrict__ xs,
    const float* __restrict__ xv,
    const float* __restrict__ Wp1, const float* __restrict__ bp1,
    const float* __restrict__ Wp2, const float* __restrict__ bp2,
    const float* __restrict__ Wc1, const float* __restrict__ bc1,
    const float* __restrict__ Wc2, const float* __restrict__ bc2,
    float* __restrict__ out, int n)
{
    // packed weights: Wp1[150]@0 bp1[10]@150 Wp2[50]@160 bp2[5]@210
    //                 Wc1[25]@215 bc1[5]@240 Wc2[10]@245 bc2[2]@255
    __shared__ float sW[257];
    const int tid = threadIdx.x;
    if (tid < 150) sW[tid] = Wp1[tid];
    if (tid < 10)  sW[150 + tid] = bp1[tid];
    if (tid < 50)  sW[160 + tid] = Wp2[tid];
    if (tid < 5)   sW[210 + tid] = bp2[tid];
    if (tid < 25)  sW[215 + tid] = Wc1[tid];
    if (tid < 5)   sW[240 + tid] = bc1[tid];
    if (tid < 10)  sW[245 + tid] = Wc2[tid];
    if (tid < 2)   sW[255 + tid] = bc2[tid];
    __syncthreads();

    const int node = blockIdx.x * 256 + tid;
    if (node >= n) return;
    const size_t n5 = (size_t)node * KOUT;

    float h[15];
#pragma unroll
    for (int k = 0; k < 5; ++k) {
        h[k]      = xp[n5 + k];
        h[5 + k]  = xs[n5 + k];
        h[10 + k] = xv[n5 + k];
    }

    float t1[10];
#pragma unroll
    for (int o = 0; o < 10; ++o) {
        float a = sW[150 + o];
#pragma unroll
        for (int i = 0; i < 15; ++i) a += h[i] * sW[i * 10 + o];
        t1[o] = (a >= 0.f) ? a : 0.1f * a;
    }

    float t2[5];
#pragma unroll
    for (int o = 0; o < 5; ++o) {
        float a = sW[210 + o];
#pragma unroll
        for (int i = 0; i < 10; ++i) a += t1[i] * sW[160 + i * 5 + o];
        t2[o] = a;                       // no activation after Wp2
    }

    float t3[5];
#pragma unroll
    for (int o = 0; o < 5; ++o) {
        float a = sW[240 + o];
#pragma unroll
        for (int i = 0; i < 5; ++i) a += t2[i] * sW[215 + i * 5 + o];
        t3[o] = (a >= 0.f) ? a : 0.1f * a;
    }

    float o0 = sW[255], o1 = sW[256];
#pragma unroll
    for (int i = 0; i < 5; ++i) {
        o0 += t3[i] * sW[245 + i * 2 + 0];
        o1 += t3[i] * sW[245 + i * 2 + 1];
    }
    out[(size_t)node * 2 + 0] = o0;
    out[(size_t)node * 2 + 1] = o1;
}

// ---------------------------------------------------------------------------
extern "C" void kernel_launch(void* const* d_in, const int* in_sizes, int n_in,
                              void* d_out, int out_size, void* d_ws, size_t ws_size,
                              hipStream_t stream)
{
    const float* x = (const float*)d_in[0];
    const int n = in_sizes[0] / KIN;          // 1,000,000
    const int E = in_sizes[1] / 2;            // 8,000,000

    const int* ei[3] = { (const int*)d_in[1], (const int*)d_in[2], (const int*)d_in[3] };
    const float *Wl[3], *Wr[3], *att[3], *bias[3];
    for (int r = 0; r < 3; ++r) {
        const int base = 4 + r * 4;
        Wl[r]   = (const float*)d_in[base + 0];
        Wr[r]   = (const float*)d_in[base + 1];
        att[r]  = (const float*)d_in[base + 2];
        bias[r] = (const float*)d_in[base + 3];
    }
    const float* Wp1 = (const float*)d_in[16];
    const float* bp1 = (const float*)d_in[17];
    const float* Wp2 = (const float*)d_in[18];
    const float* bp2 = (const float*)d_in[19];
    const float* Wc1 = (const float*)d_in[20];
    const float* bc1 = (const float*)d_in[21];
    const float* Wc2 = (const float*)d_in[22];
    const float* bc2 = (const float*)d_in[23];

    // workspace layout (floats):
    //   xout[3][n][5] (acc, finalized in place) | xl[n][5] | xr[n][5] | denom[n]
    float* ws    = (float*)d_ws;
    float* xout  = ws;
    float* xl    = ws + (size_t)15 * n;
    float* xr    = xl + (size_t)5 * n;
    float* denom = xr + (size_t)5 * n;

    const int nb_node = (n + 255) / 256;
    const int nb_edge = (E + 255) / 256;

    for (int r = 0; r < 3; ++r) {
        float* acc = xout + (size_t)r * 5 * n;
        k_node<<<nb_node, 256, 0, stream>>>(x, Wl[r], Wr[r], att[r],
                                            xl, xr, denom, acc, n);
        k_edge<<<nb_edge, 256, 0, stream>>>(ei[r], E, xl, xr, att[r], denom, acc);
        k_fin<<<nb_node, 256, 0, stream>>>(acc, denom, bias[r], n);
    }

    k_mlp<<<nb_node, 256, 0, stream>>>(xout, xout + (size_t)5 * n, xout + (size_t)10 * n,
                                       Wp1, bp1, Wp2, bp2, Wc1, bc1, Wc2, bc2,
                                       (float*)d_out, n);
}